// Round 6
// baseline (92.245 us; speedup 1.0000x reference)
//
#include <hip/hip_runtime.h>
#include <cstdint>

// B=4, N=256, D=128, HID=128, IN_DIM=516.
// G[i,j,h] = [|hi-hj| ; hi*hj] @ W1[256:512]  (K=256 fp8 MFMA, W x256) -- symmetric in (i,j)
// pre' = 256*pre = acc + PiB'[i,h] + Pjf'[j,h] + scal'(p)@W1[512:516]
// R12 epilogue MFMA (per mi,ni,dir): C = acc; A k=0..3 scal', k=4,5 indicator(row>>3);
//   B k=0..3 W1[512:516], k=4,5 {P_I-side'[2mi],[2mi+1]}  -> SF/SM = acc+scal+I-side.
//   J-side (pjJ fwd / piJ mir) stays scalar (R11's J-fold = +24 VGPR = spill regression).
// L = relu(pre') @ (W2/256) + b2 ; out[i,j]=out[j,i]=0.5*(L_f+L_m); diag -1e9.
// R13 = R12 + main-loop B-fragment register PREFETCH (gB[8] 32 VGPR -> 2x uint4 rolling,
//       rolled ks-loop) freeing VGPR to ~75 -> LB(256,6): 6 blocks/CU (LDS 25.9KB x6 fits).

typedef float f32x4 __attribute__((ext_vector_type(4)));
typedef short bf16x8 __attribute__((ext_vector_type(8)));

#define INV256 0.00390625f

__device__ __forceinline__ uint32_t pk4(float a, float b, float c, float d) {
  uint32_t u = __builtin_amdgcn_cvt_pk_fp8_f32(a, b, 0, false);
  u = __builtin_amdgcn_cvt_pk_fp8_f32(c, d, u, true);
  return u;
}
__device__ __forceinline__ uint32_t pkbf2(float lo, float hi) {
  uint32_t l = __builtin_bit_cast(uint32_t, lo);
  uint32_t h = __builtin_bit_cast(uint32_t, hi);
  return (l >> 16) | (h & 0xffff0000u);
}
// round-to-nearest-even bf16 pack
__device__ __forceinline__ uint32_t rnebf(float x) {
  uint32_t u = __builtin_bit_cast(uint32_t, x);
  return (u + 0x7fffu + ((u >> 16) & 1u)) >> 16;
}
__device__ __forceinline__ uint32_t pkbf2r(float lo, float hi) {
  return rnebf(lo) | (rnebf(hi) << 16);
}
__device__ __forceinline__ float ulo(uint32_t u) {
  return __builtin_bit_cast(float, u << 16);
}
__device__ __forceinline__ float uhi(uint32_t u) {
  return __builtin_bit_cast(float, u & 0xffff0000u);
}
__device__ __forceinline__ long mk64(uint32_t lo, uint32_t hi) {
  return (long)((((unsigned long long)hi) << 32) | lo);
}
__device__ __forceinline__ bf16x8 mkbf8(uint32_t a, uint32_t b, uint32_t c, uint32_t d) {
  uint4 u;
  u.x = a; u.y = b; u.z = c; u.w = d;
  return __builtin_bit_cast(bf16x8, u);
}

// bid<32: pack fp8 B-image (lane-linear MFMA fragment order, values W1*256), 128 threads
// bid in [32,96): bf16 MFMA GEMM: rows 16/block, Ppk[row][h] = {bf16 PiB' | bf16 Pjf'}
//   PiB' = 256*(node@W1[0:128] + b1), Pjf' = 256*(node@W1[128:256]).
__global__ __launch_bounds__(256) void pre_k(const float* __restrict__ node,
                                             const float* __restrict__ W1,
                                             const float* __restrict__ b1,
                                             uint32_t* __restrict__ Ppk,
                                             uint32_t* __restrict__ W1f8) {
  int bid = blockIdx.x;
  int tid = threadIdx.x;
  if (bid < 32) {
    if (tid < 128) {
      int ks = bid >> 2, nip = (bid >> 1) & 1, wn = bid & 1;
      int lane = tid & 63, nilow = tid >> 6;
      int quad = lane >> 4, col = lane & 15;
      int h = wn * 64 + (nip * 2 + nilow) * 16 + col;
      int k0 = ks * 32 + quad * 8;
      float w[8];
#pragma unroll
      for (int t = 0; t < 8; ++t) w[t] = W1[(256 + k0 + t) * 128 + h] * 256.0f;
      uint2 u;
      u.x = pk4(w[0], w[1], w[2], w[3]);
      u.y = pk4(w[4], w[5], w[6], w[7]);
      reinterpret_cast<uint2*>(W1f8)[(bid * 64 + lane) * 2 + nilow] = u;
    }
    return;
  }
  // ---- GEMM part: block = 16 node rows, 4 waves x 64 h-cols, K=128 ----
  __shared__ float sC[16 * 264];  // +8 pad: rows offset 8 banks
  const int gb = bid - 32;        // 0..63
  const int gr0 = gb * 16;
  const int w = tid >> 6, lane = tid & 63, col = lane & 15, quad = lane >> 4;

  // A-frags: A[row=col][k=ks*32+quad*8+t] = node[gr0+col][k], RNE bf16
  bf16x8 Af[4];
  const float* arow = node + (size_t)(gr0 + col) * 128 + quad * 8;
#pragma unroll
  for (int ks = 0; ks < 4; ++ks) {
    float4 a0 = *reinterpret_cast<const float4*>(arow + ks * 32);
    float4 a1 = *reinterpret_cast<const float4*>(arow + ks * 32 + 4);
    Af[ks] = mkbf8(pkbf2r(a0.x, a0.y), pkbf2r(a0.z, a0.w),
                   pkbf2r(a1.x, a1.y), pkbf2r(a1.z, a1.w));
  }
  // waves 0,1 -> cols 0..127 (slab W1[0:128] -> PiB), waves 2,3 -> cols 128..255 (Pjf)
  const int colbase = w * 64;
  const float* wbase = W1 + (size_t)((w >> 1) * 128) * 128;
#pragma unroll
  for (int ni = 0; ni < 4; ++ni) {
    const int hh = (colbase + ni * 16 + col) & 127;
    f32x4 acc = {};
#pragma unroll
    for (int ks = 0; ks < 4; ++ks) {
      const float* wp = wbase + (size_t)(ks * 32 + quad * 8) * 128 + hh;
      bf16x8 Bf = mkbf8(pkbf2r(wp[0], wp[128]), pkbf2r(wp[256], wp[384]),
                        pkbf2r(wp[512], wp[640]), pkbf2r(wp[768], wp[896]));
      acc = __builtin_amdgcn_mfma_f32_16x16x32_bf16(Af[ks], Bf, acc, 0, 0, 0);
    }
#pragma unroll
    for (int r = 0; r < 4; ++r)
      sC[(quad * 4 + r) * 264 + colbase + ni * 16 + col] = acc[r];
  }
  __syncthreads();
  // pack: thread (row=tid>>4, hq=tid&15) -> 8 h, Ppk = {bf16 PiB' | bf16 Pjf'}
  {
    const int row = tid >> 4, hq = tid & 15;
    uint32_t ov[8];
#pragma unroll
    for (int hh = 0; hh < 8; ++hh) {
      int h = hq * 8 + hh;
      float pib = 256.f * (sC[row * 264 + h] + b1[h]);
      float pjf = 256.f * sC[row * 264 + 128 + h];
      ov[hh] = pkbf2r(pib, pjf);
    }
    uint4* dst = reinterpret_cast<uint4*>(Ppk + (size_t)(gr0 + row) * 128 + hq * 8);
    dst[0] = *reinterpret_cast<uint4*>(&ov[0]);
    dst[1] = *reinterpret_cast<uint4*>(&ov[4]);
  }
}

// grid 2112 = b(4) * 528 unordered 8-group pairs (I<=J). 64 pairs/block, K=256 fp8.
// waves: wn2 = tid>>6 owns h-cols [wn2*32, wn2*32+32) (ni tiles 2wn2, 2wn2+1).
__global__ __launch_bounds__(256, 6) void main_k(
    const float* __restrict__ node, const float* __restrict__ baseL,
    const float* __restrict__ compL, const float* __restrict__ W1,
    const float* __restrict__ W2, const float* __restrict__ b2,
    const uint32_t* __restrict__ W1f8, const uint32_t* __restrict__ Ppk,
    float* __restrict__ out) {
  // sF: [ks 0..7][mi 0..3][q 0..3][scol 0..15] 8B, scol=(col+2q+4(ks&3))&15 -> 16384 B
  //   (overlaid post-MFMA by sP: [64 pairs][40] fp32 partials, fwd@0..15, mir@20..35)
  // sPP: [16 rows][132] u32 {bf16 PiB' | bf16 Pjf'} (rows 0-7 I-group, 8-15 J-group)
  // sScal: [64 pairs] uint4 bf16x2 {bl',sig'}{cl',sig'} fwd then mirror
  __shared__ __align__(16) char smem[16384 + 8448 + 1024];
  char* sF = smem;
  uint32_t* sPP = reinterpret_cast<uint32_t*>(smem + 16384);
  uint4* sScal = reinterpret_cast<uint4*>(smem + 16384 + 8448);
  float* sP = reinterpret_cast<float*>(smem);  // overlay

  const int tid = threadIdx.x;
  const int bx = blockIdx.x;
  const int b = bx / 528;
  const int t = bx - b * 528;
  int tI = (int)((65.0f - sqrtf(4225.0f - 8.0f * (float)t)) * 0.5f);
  tI = (tI < 0) ? 0 : (tI > 31 ? 31 : tI);
  while (((65 * tI - tI * tI) >> 1) > t) --tI;
  while (tI < 31 && ((65 * (tI + 1) - (tI + 1) * (tI + 1)) >> 1) <= t) ++tI;
  const int tJ = tI + (t - ((65 * tI - tI * tI) >> 1));
  const int I0 = tI * 8, J0 = tJ * 8;
  const int rowB = b * 256;

  const int lane = tid & 63;
  const int wn2 = tid >> 6;
  const int col = lane & 15, quad = lane >> 4;
  const int uB = ((wn2 & 1) << 1) | (wn2 >> 1);
  const uint4* W1v = reinterpret_cast<const uint4*>(W1f8);

  // ---- stage sPP: pure copy of pre-packed Ppk rows (16 x 128 u32) ----
#pragma unroll
  for (int it = 0; it < 2; ++it) {
    int fidx = it * 256 + tid;  // 512 uint4 slots
    int row = fidx >> 5, q = fidx & 31;
    int gr = rowB + ((row < 8) ? (I0 + row) : (J0 + row - 8));
    uint4 u = reinterpret_cast<const uint4*>(Ppk + (size_t)gr * 128)[q];
    *reinterpret_cast<uint4*>(&sPP[row * 132 + q * 4]) = u;
  }

  // ---- stage scal (x256), fwd (tid<64) and mirror (tid in [64,128)) ----
  if (tid < 128) {
    int p = tid & 63, dir = tid >> 6;
    int iN = I0 + (p >> 3), jN = J0 + (p & 7);
    int rr = dir ? jN : iN, cc = dir ? iN : jN;
    float bl = fminf(fmaxf(baseL[(size_t)(rowB + rr) * 256 + cc], -20.f), 20.f);
    float cl = fminf(fmaxf(compL[(size_t)(rowB + rr) * 256 + cc], -20.f), 20.f);
    uint2 u;
    u.x = pkbf2(256.f * bl, 256.f / (1.f + __expf(-bl)));
    u.y = pkbf2(256.f * cl, 256.f / (1.f + __expf(-cl)));
    *reinterpret_cast<uint2*>(reinterpret_cast<char*>(&sScal[p]) + dir * 8) = u;
  }

  // ---- per-lane epilogue constants: W2 column + epilogue-MFMA B k=0..3 rows ----
  float cW2[2];
  uint32_t w01[2], w23[2];
#pragma unroll
  for (int ni = 0; ni < 2; ++ni) {
    int h = (wn2 * 2 + ni) * 16 + col;
    w01[ni] = pkbf2r(W1[512 * 128 + h], W1[513 * 128 + h]);
    w23[ni] = pkbf2r(W1[514 * 128 + h], W1[515 * 128 + h]);
    cW2[ni] = W2[h] * INV256;
  }
  const float b2v = b2[0];

  // ---- F-build: 64 pairs x 256 k fp8, node read direct from global (L1-hot) ----
  {
    const int d4 = tid & 31;  // float4 index in 128 dims
    const int rr = tid >> 5;  // j-row 0..7
    const int ks1 = d4 >> 3, qd = (d4 >> 1) & 3, kb = (d4 & 1) * 4;
    const int scolbase = 2 * qd + 4 * ks1;  // ks-rotation -> 2-way (free) write conflicts
    const float4 hj = *reinterpret_cast<const float4*>(node + (size_t)(rowB + J0 + rr) * 128 + d4 * 4);
#pragma unroll
    for (int ii = 0; ii < 8; ++ii) {
      const float4 hi = *reinterpret_cast<const float4*>(node + (size_t)(rowB + I0 + ii) * 128 + d4 * 4);
      uint32_t du = pk4(fabsf(hi.x - hj.x), fabsf(hi.y - hj.y),
                        fabsf(hi.z - hj.z), fabsf(hi.w - hj.w));
      uint32_t pu = pk4(hi.x * hj.x, hi.y * hj.y, hi.z * hj.z, hi.w * hj.w);
      int p = ii * 8 + rr;
      int colp = p & 15, mi = p >> 4;
      int scol = (colp + scolbase) & 15;
      uint32_t addr = mi * 512 + qd * 128 + scol * 8 + kb;
      *reinterpret_cast<uint32_t*>(sF + ks1 * 2048 + addr) = du;
      *reinterpret_cast<uint32_t*>(sF + (ks1 + 4) * 2048 + addr) = pu;
    }
  }
  __syncthreads();

  // ---- MFMA: acc[4 mi][2 ni], K=256; A from swizzled LDS, B prefetched (rolling 2) ----
  f32x4 acc[4][2] = {};
  uint4 gBc = W1v[(size_t)uB * 64 + lane];
#pragma unroll 1
  for (int ks = 0; ks < 8; ++ks) {
    uint4 gBn = W1v[(size_t)(((ks + 1) & 7) * 4 + uB) * 64 + lane];  // next (L2-hot)
    long bb0 = mk64(gBc.x, gBc.y);
    long bb1 = mk64(gBc.z, gBc.w);
    const int ascol = (col + 2 * quad + 4 * (ks & 3)) & 15;
    const char* aks = sF + ks * 2048 + quad * 128 + ascol * 8;
#pragma unroll
    for (int mi = 0; mi < 4; ++mi) {
      uint2 av = *reinterpret_cast<const uint2*>(aks + mi * 512);
      long aa = mk64(av.x, av.y);
      acc[mi][0] = __builtin_amdgcn_mfma_f32_16x16x32_fp8_fp8(aa, bb0, acc[mi][0], 0, 0, 0);
      acc[mi][1] = __builtin_amdgcn_mfma_f32_16x16x32_fp8_fp8(aa, bb1, acc[mi][1], 0, 0, 0);
    }
    gBc = gBn;
  }
  __syncthreads();  // sF reads done -> sP overlay writable

  // ---- epilogue: SF/SM = acc + scal'@W + I-side via MFMA (C=acc, k=4,5 indicator);
  //      J-side (pjJ fwd / piJ mir) scalar. A row = col; quads!=0 have A=0 so B free.
  uint32_t uJ[4][2];
#pragma unroll
  for (int r = 0; r < 4; ++r)
#pragma unroll
    for (int ni = 0; ni < 2; ++ni)
      uJ[r][ni] = sPP[(8 + (quad & 1) * 4 + r) * 132 + (wn2 * 2 + ni) * 16 + col];

  // indicator element (k=4: row<8 -> i0, k=5: row>=8 -> i1), bf16 1.0 packed
  const uint32_t IND = (col < 8) ? 0x00003F80u : 0x3F800000u;
  const uint32_t qz = (quad == 0) ? 0xffffffffu : 0u;  // quad0 mask for A elements

#pragma unroll
  for (int mi = 0; mi < 4; ++mi) {
    uint4 sc4 = sScal[mi * 16 + col];
    bf16x8 af = mkbf8(sc4.x & qz, sc4.y & qz, IND & qz, 0u);
    bf16x8 am = mkbf8(sc4.z & qz, sc4.w & qz, IND & qz, 0u);
    f32x4 SF[2], SM[2];
#pragma unroll
    for (int ni = 0; ni < 2; ++ni) {
      const int hx = (wn2 * 2 + ni) * 16 + col;
      uint32_t i0 = sPP[(mi * 2) * 132 + hx];
      uint32_t i1 = sPP[(mi * 2 + 1) * 132 + hx];
      uint32_t bIf = (i0 & 0xffffu) | (i1 << 16);      // {PiB'[2mi], PiB'[2mi+1]}
      uint32_t bIm = (i0 >> 16) | (i1 & 0xffff0000u);  // {Pjf'[2mi], Pjf'[2mi+1]}
      bf16x8 Bf_ = mkbf8(w01[ni], w23[ni], bIf, 0u);
      bf16x8 Bm_ = mkbf8(w01[ni], w23[ni], bIm, 0u);
      SF[ni] = __builtin_amdgcn_mfma_f32_16x16x32_bf16(af, Bf_, acc[mi][ni], 0, 0, 0);
      SM[ni] = __builtin_amdgcn_mfma_f32_16x16x32_bf16(am, Bm_, acc[mi][ni], 0, 0, 0);
    }

#pragma unroll
    for (int r = 0; r < 4; ++r) {
      int p = mi * 16 + quad * 4 + r;  // C/D: pair row = quad*4 + r
      float vf = 0.f, vm = 0.f;
#pragma unroll
      for (int ni = 0; ni < 2; ++ni) {
        float piJ = ulo(uJ[r][ni]), pjJ = uhi(uJ[r][ni]);
        float pf = SF[ni][r] + pjJ;
        float pm = SM[ni][r] + piJ;
        vf = fmaf(fmaxf(pf, 0.f), cW2[ni], vf);
        vm = fmaf(fmaxf(pm, 0.f), cW2[ni], vm);
      }
      vf += __shfl_xor(vf, 1);
      vf += __shfl_xor(vf, 2);
      vm += __shfl_xor(vm, 1);
      vm += __shfl_xor(vm, 2);
      if ((col & 3) == 0) {
        int part = wn2 * 4 + (col >> 2);
        sP[p * 40 + part] = vf;
        sP[p * 40 + 20 + part] = vm;
      }
    }
  }
  __syncthreads();

  // ---- final: sum 16 fwd + 16 mirror partials, symmetric store ----
  if (tid < 64) {
    int p = tid;
    const float4* pf4 = reinterpret_cast<const float4*>(sP + p * 40);
    const float4* pm4 = reinterpret_cast<const float4*>(sP + p * 40 + 20);
    float4 fa = pf4[0], fb = pf4[1], fc = pf4[2], fd = pf4[3];
    float4 ma = pm4[0], mb = pm4[1], mc = pm4[2], md = pm4[3];
    float sumF = (fa.x + fa.y + fa.z + fa.w) + (fb.x + fb.y + fb.z + fb.w) +
                 (fc.x + fc.y + fc.z + fc.w) + (fd.x + fd.y + fd.z + fd.w);
    float sumM = (ma.x + ma.y + ma.z + ma.w) + (mb.x + mb.y + mb.z + mb.w) +
                 (mc.x + mc.y + mc.z + mc.w) + (md.x + md.y + md.z + md.w);
    float val = 0.5f * (sumF + sumM) + b2v;
    int iN = I0 + (p >> 3), jN = J0 + (p & 7);
    if (iN == jN) val = -1e9f;
    out[(size_t)(rowB + iN) * 256 + jN] = val;
    out[(size_t)(rowB + jN) * 256 + iN] = val;
  }
}

extern "C" void kernel_launch(void* const* d_in, const int* in_sizes, int n_in,
                              void* d_out, int out_size, void* d_ws, size_t ws_size,
                              hipStream_t stream) {
  const float* node = (const float*)d_in[0];   // [4,256,128]
  const float* baseL = (const float*)d_in[1];  // [4,256,256]
  const float* compL = (const float*)d_in[2];  // [4,256,256]
  const float* W1 = (const float*)d_in[3];     // [516,128]
  const float* b1 = (const float*)d_in[4];     // [128]
  const float* W2 = (const float*)d_in[5];     // [128,1]
  const float* b2 = (const float*)d_in[6];     // [1]
  float* out = (float*)d_out;                  // [4,256,256] fp32

  char* ws = (char*)d_ws;
  uint32_t* Ppk = (uint32_t*)ws;                   // 512 KB packed {PiB'|Pjf'}
  uint32_t* W1f8 = (uint32_t*)(ws + (512 << 10));  // 32 KB

  pre_k<<<96, 256, 0, stream>>>(node, W1, b1, Ppk, W1f8);
  main_k<<<2112, 256, 0, stream>>>(node, baseL, compL, W1, W2, b2, W1f8, Ppk, out);
}

// Round 7
// 90.239 us; speedup vs baseline: 1.0222x; 1.0222x over previous
//
#include <hip/hip_runtime.h>
#include <cstdint>

// B=4, N=256, D=128, HID=128, IN_DIM=516.
// G[i,j,h] = [|hi-hj| ; hi*hj] @ W1[256:512]  (K=256 fp8 MFMA, W x256) -- symmetric in (i,j)
// pre' = 256*pre = acc + PiB'[i,h] + Pjf'[j,h] + scal'(p)@W1[512:516]
// Epilogue MFMA (per mi,ni,dir): C = acc; A k=0..3 scal', k=4,5 indicator(row>>3);
//   B k=0..3 W1[512:516], k=4,5 {P_I-side'[2mi],[2mi+1]}  -> SF/SM = acc+scal+I-side.
//   J-side (pjJ fwd / piJ mir) stays scalar (R11's J-fold = +24 VGPR = spill regression).
// L = relu(pre') @ (W2/256) + b2 ; out[i,j]=out[j,i]=0.5*(L_f+L_m); diag -1e9.
// R14 = exact R12 revert (best: 90.37 raw / ~8.2 us normalized).
//   R13's rolling B-prefetch + LB(256,6) regressed ~3 us: rolled ks-loop put a vmcnt
//   dependency inside the MFMA loop (compiler's unrolled gB[8] form was already optimal).

typedef float f32x4 __attribute__((ext_vector_type(4)));
typedef short bf16x8 __attribute__((ext_vector_type(8)));

#define INV256 0.00390625f

__device__ __forceinline__ uint32_t pk4(float a, float b, float c, float d) {
  uint32_t u = __builtin_amdgcn_cvt_pk_fp8_f32(a, b, 0, false);
  u = __builtin_amdgcn_cvt_pk_fp8_f32(c, d, u, true);
  return u;
}
__device__ __forceinline__ uint32_t pkbf2(float lo, float hi) {
  uint32_t l = __builtin_bit_cast(uint32_t, lo);
  uint32_t h = __builtin_bit_cast(uint32_t, hi);
  return (l >> 16) | (h & 0xffff0000u);
}
// round-to-nearest-even bf16 pack
__device__ __forceinline__ uint32_t rnebf(float x) {
  uint32_t u = __builtin_bit_cast(uint32_t, x);
  return (u + 0x7fffu + ((u >> 16) & 1u)) >> 16;
}
__device__ __forceinline__ uint32_t pkbf2r(float lo, float hi) {
  return rnebf(lo) | (rnebf(hi) << 16);
}
__device__ __forceinline__ float ulo(uint32_t u) {
  return __builtin_bit_cast(float, u << 16);
}
__device__ __forceinline__ float uhi(uint32_t u) {
  return __builtin_bit_cast(float, u & 0xffff0000u);
}
__device__ __forceinline__ long mk64(uint32_t lo, uint32_t hi) {
  return (long)((((unsigned long long)hi) << 32) | lo);
}
__device__ __forceinline__ bf16x8 mkbf8(uint32_t a, uint32_t b, uint32_t c, uint32_t d) {
  uint4 u;
  u.x = a; u.y = b; u.z = c; u.w = d;
  return __builtin_bit_cast(bf16x8, u);
}

// bid<32: pack fp8 B-image (lane-linear MFMA fragment order, values W1*256), 128 threads
// bid in [32,96): bf16 MFMA GEMM: rows 16/block, Ppk[row][h] = {bf16 PiB' | bf16 Pjf'}
//   PiB' = 256*(node@W1[0:128] + b1), Pjf' = 256*(node@W1[128:256]).
__global__ __launch_bounds__(256) void pre_k(const float* __restrict__ node,
                                             const float* __restrict__ W1,
                                             const float* __restrict__ b1,
                                             uint32_t* __restrict__ Ppk,
                                             uint32_t* __restrict__ W1f8) {
  int bid = blockIdx.x;
  int tid = threadIdx.x;
  if (bid < 32) {
    if (tid < 128) {
      int ks = bid >> 2, nip = (bid >> 1) & 1, wn = bid & 1;
      int lane = tid & 63, nilow = tid >> 6;
      int quad = lane >> 4, col = lane & 15;
      int h = wn * 64 + (nip * 2 + nilow) * 16 + col;
      int k0 = ks * 32 + quad * 8;
      float w[8];
#pragma unroll
      for (int t = 0; t < 8; ++t) w[t] = W1[(256 + k0 + t) * 128 + h] * 256.0f;
      uint2 u;
      u.x = pk4(w[0], w[1], w[2], w[3]);
      u.y = pk4(w[4], w[5], w[6], w[7]);
      reinterpret_cast<uint2*>(W1f8)[(bid * 64 + lane) * 2 + nilow] = u;
    }
    return;
  }
  // ---- GEMM part: block = 16 node rows, 4 waves x 64 h-cols, K=128 ----
  __shared__ float sC[16 * 264];  // +8 pad: rows offset 8 banks
  const int gb = bid - 32;        // 0..63
  const int gr0 = gb * 16;
  const int w = tid >> 6, lane = tid & 63, col = lane & 15, quad = lane >> 4;

  // A-frags: A[row=col][k=ks*32+quad*8+t] = node[gr0+col][k], RNE bf16
  bf16x8 Af[4];
  const float* arow = node + (size_t)(gr0 + col) * 128 + quad * 8;
#pragma unroll
  for (int ks = 0; ks < 4; ++ks) {
    float4 a0 = *reinterpret_cast<const float4*>(arow + ks * 32);
    float4 a1 = *reinterpret_cast<const float4*>(arow + ks * 32 + 4);
    Af[ks] = mkbf8(pkbf2r(a0.x, a0.y), pkbf2r(a0.z, a0.w),
                   pkbf2r(a1.x, a1.y), pkbf2r(a1.z, a1.w));
  }
  // waves 0,1 -> cols 0..127 (slab W1[0:128] -> PiB), waves 2,3 -> cols 128..255 (Pjf)
  const int colbase = w * 64;
  const float* wbase = W1 + (size_t)((w >> 1) * 128) * 128;
#pragma unroll
  for (int ni = 0; ni < 4; ++ni) {
    const int hh = (colbase + ni * 16 + col) & 127;
    f32x4 acc = {};
#pragma unroll
    for (int ks = 0; ks < 4; ++ks) {
      const float* wp = wbase + (size_t)(ks * 32 + quad * 8) * 128 + hh;
      bf16x8 Bf = mkbf8(pkbf2r(wp[0], wp[128]), pkbf2r(wp[256], wp[384]),
                        pkbf2r(wp[512], wp[640]), pkbf2r(wp[768], wp[896]));
      acc = __builtin_amdgcn_mfma_f32_16x16x32_bf16(Af[ks], Bf, acc, 0, 0, 0);
    }
#pragma unroll
    for (int r = 0; r < 4; ++r)
      sC[(quad * 4 + r) * 264 + colbase + ni * 16 + col] = acc[r];
  }
  __syncthreads();
  // pack: thread (row=tid>>4, hq=tid&15) -> 8 h, Ppk = {bf16 PiB' | bf16 Pjf'}
  {
    const int row = tid >> 4, hq = tid & 15;
    uint32_t ov[8];
#pragma unroll
    for (int hh = 0; hh < 8; ++hh) {
      int h = hq * 8 + hh;
      float pib = 256.f * (sC[row * 264 + h] + b1[h]);
      float pjf = 256.f * sC[row * 264 + 128 + h];
      ov[hh] = pkbf2r(pib, pjf);
    }
    uint4* dst = reinterpret_cast<uint4*>(Ppk + (size_t)(gr0 + row) * 128 + hq * 8);
    dst[0] = *reinterpret_cast<uint4*>(&ov[0]);
    dst[1] = *reinterpret_cast<uint4*>(&ov[4]);
  }
}

// grid 2112 = b(4) * 528 unordered 8-group pairs (I<=J). 64 pairs/block, K=256 fp8.
// waves: wn2 = tid>>6 owns h-cols [wn2*32, wn2*32+32) (ni tiles 2wn2, 2wn2+1).
__global__ __launch_bounds__(256, 5) void main_k(
    const float* __restrict__ node, const float* __restrict__ baseL,
    const float* __restrict__ compL, const float* __restrict__ W1,
    const float* __restrict__ W2, const float* __restrict__ b2,
    const uint32_t* __restrict__ W1f8, const uint32_t* __restrict__ Ppk,
    float* __restrict__ out) {
  // sF: [ks 0..7][mi 0..3][q 0..3][scol 0..15] 8B, scol=(col+2q+4(ks&3))&15 -> 16384 B
  //   (overlaid post-MFMA by sP: [64 pairs][40] fp32 partials, fwd@0..15, mir@20..35)
  // sPP: [16 rows][132] u32 {bf16 PiB' | bf16 Pjf'} (rows 0-7 I-group, 8-15 J-group)
  // sScal: [64 pairs] uint4 bf16x2 {bl',sig'}{cl',sig'} fwd then mirror
  __shared__ __align__(16) char smem[16384 + 8448 + 1024];
  char* sF = smem;
  uint32_t* sPP = reinterpret_cast<uint32_t*>(smem + 16384);
  uint4* sScal = reinterpret_cast<uint4*>(smem + 16384 + 8448);
  float* sP = reinterpret_cast<float*>(smem);  // overlay

  const int tid = threadIdx.x;
  const int bx = blockIdx.x;
  const int b = bx / 528;
  const int t = bx - b * 528;
  int tI = (int)((65.0f - sqrtf(4225.0f - 8.0f * (float)t)) * 0.5f);
  tI = (tI < 0) ? 0 : (tI > 31 ? 31 : tI);
  while (((65 * tI - tI * tI) >> 1) > t) --tI;
  while (tI < 31 && ((65 * (tI + 1) - (tI + 1) * (tI + 1)) >> 1) <= t) ++tI;
  const int tJ = tI + (t - ((65 * tI - tI * tI) >> 1));
  const int I0 = tI * 8, J0 = tJ * 8;
  const int rowB = b * 256;

  const int lane = tid & 63;
  const int wn2 = tid >> 6;
  const int col = lane & 15, quad = lane >> 4;

  // ---- B-fragments to registers (32 VGPR), L2-broadcast, held all kernel ----
  const int uB = ((wn2 & 1) << 1) | (wn2 >> 1);
  uint4 gB[8];
#pragma unroll
  for (int ks = 0; ks < 8; ++ks)
    gB[ks] = reinterpret_cast<const uint4*>(W1f8)[(ks * 4 + uB) * 64 + lane];

  // ---- stage sPP: pure copy of pre-packed Ppk rows (16 x 128 u32) ----
#pragma unroll
  for (int it = 0; it < 2; ++it) {
    int fidx = it * 256 + tid;  // 512 uint4 slots
    int row = fidx >> 5, q = fidx & 31;
    int gr = rowB + ((row < 8) ? (I0 + row) : (J0 + row - 8));
    uint4 u = reinterpret_cast<const uint4*>(Ppk + (size_t)gr * 128)[q];
    *reinterpret_cast<uint4*>(&sPP[row * 132 + q * 4]) = u;
  }

  // ---- stage scal (x256), fwd (tid<64) and mirror (tid in [64,128)) ----
  if (tid < 128) {
    int p = tid & 63, dir = tid >> 6;
    int iN = I0 + (p >> 3), jN = J0 + (p & 7);
    int rr = dir ? jN : iN, cc = dir ? iN : jN;
    float bl = fminf(fmaxf(baseL[(size_t)(rowB + rr) * 256 + cc], -20.f), 20.f);
    float cl = fminf(fmaxf(compL[(size_t)(rowB + rr) * 256 + cc], -20.f), 20.f);
    uint2 u;
    u.x = pkbf2(256.f * bl, 256.f / (1.f + __expf(-bl)));
    u.y = pkbf2(256.f * cl, 256.f / (1.f + __expf(-cl)));
    *reinterpret_cast<uint2*>(reinterpret_cast<char*>(&sScal[p]) + dir * 8) = u;
  }

  // ---- per-lane epilogue constants: W2 column + epilogue-MFMA B k=0..3 rows ----
  float cW2[2];
  uint32_t w01[2], w23[2];
#pragma unroll
  for (int ni = 0; ni < 2; ++ni) {
    int h = (wn2 * 2 + ni) * 16 + col;
    w01[ni] = pkbf2r(W1[512 * 128 + h], W1[513 * 128 + h]);
    w23[ni] = pkbf2r(W1[514 * 128 + h], W1[515 * 128 + h]);
    cW2[ni] = W2[h] * INV256;
  }
  const float b2v = b2[0];

  // ---- F-build: 64 pairs x 256 k fp8, node read direct from global (L1-hot) ----
  {
    const int d4 = tid & 31;  // float4 index in 128 dims
    const int rr = tid >> 5;  // j-row 0..7
    const int ks1 = d4 >> 3, qd = (d4 >> 1) & 3, kb = (d4 & 1) * 4;
    const int scolbase = 2 * qd + 4 * ks1;  // ks-rotation -> 2-way (free) write conflicts
    const float4 hj = *reinterpret_cast<const float4*>(node + (size_t)(rowB + J0 + rr) * 128 + d4 * 4);
#pragma unroll
    for (int ii = 0; ii < 8; ++ii) {
      const float4 hi = *reinterpret_cast<const float4*>(node + (size_t)(rowB + I0 + ii) * 128 + d4 * 4);
      uint32_t du = pk4(fabsf(hi.x - hj.x), fabsf(hi.y - hj.y),
                        fabsf(hi.z - hj.z), fabsf(hi.w - hj.w));
      uint32_t pu = pk4(hi.x * hj.x, hi.y * hj.y, hi.z * hj.z, hi.w * hj.w);
      int p = ii * 8 + rr;
      int colp = p & 15, mi = p >> 4;
      int scol = (colp + scolbase) & 15;
      uint32_t addr = mi * 512 + qd * 128 + scol * 8 + kb;
      *reinterpret_cast<uint32_t*>(sF + ks1 * 2048 + addr) = du;
      *reinterpret_cast<uint32_t*>(sF + (ks1 + 4) * 2048 + addr) = pu;
    }
  }
  __syncthreads();

  // ---- MFMA: acc[4 mi][2 ni], K=256; A from swizzled LDS, B from registers ----
  f32x4 acc[4][2] = {};
#pragma unroll
  for (int ks = 0; ks < 8; ++ks) {
    long bb0 = mk64(gB[ks].x, gB[ks].y);
    long bb1 = mk64(gB[ks].z, gB[ks].w);
    const int ascol = (col + 2 * quad + 4 * (ks & 3)) & 15;
    const char* aks = sF + ks * 2048 + quad * 128 + ascol * 8;
#pragma unroll
    for (int mi = 0; mi < 4; ++mi) {
      uint2 av = *reinterpret_cast<const uint2*>(aks + mi * 512);
      long aa = mk64(av.x, av.y);
      acc[mi][0] = __builtin_amdgcn_mfma_f32_16x16x32_fp8_fp8(aa, bb0, acc[mi][0], 0, 0, 0);
      acc[mi][1] = __builtin_amdgcn_mfma_f32_16x16x32_fp8_fp8(aa, bb1, acc[mi][1], 0, 0, 0);
    }
  }
  __syncthreads();  // sF reads done -> sP overlay writable

  // ---- epilogue: SF/SM = acc + scal'@W + I-side via MFMA (C=acc, k=4,5 indicator);
  //      J-side (pjJ fwd / piJ mir) scalar. A row = col; quads!=0 have A=0 so B free.
  uint32_t uJ[4][2];
#pragma unroll
  for (int r = 0; r < 4; ++r)
#pragma unroll
    for (int ni = 0; ni < 2; ++ni)
      uJ[r][ni] = sPP[(8 + (quad & 1) * 4 + r) * 132 + (wn2 * 2 + ni) * 16 + col];

  // indicator element (k=4: row<8 -> i0, k=5: row>=8 -> i1), bf16 1.0 packed
  const uint32_t IND = (col < 8) ? 0x00003F80u : 0x3F800000u;
  const uint32_t qz = (quad == 0) ? 0xffffffffu : 0u;  // quad0 mask for A elements

#pragma unroll
  for (int mi = 0; mi < 4; ++mi) {
    uint4 sc4 = sScal[mi * 16 + col];
    bf16x8 af = mkbf8(sc4.x & qz, sc4.y & qz, IND & qz, 0u);
    bf16x8 am = mkbf8(sc4.z & qz, sc4.w & qz, IND & qz, 0u);
    f32x4 SF[2], SM[2];
#pragma unroll
    for (int ni = 0; ni < 2; ++ni) {
      const int hx = (wn2 * 2 + ni) * 16 + col;
      uint32_t i0 = sPP[(mi * 2) * 132 + hx];
      uint32_t i1 = sPP[(mi * 2 + 1) * 132 + hx];
      uint32_t bIf = (i0 & 0xffffu) | (i1 << 16);      // {PiB'[2mi], PiB'[2mi+1]}
      uint32_t bIm = (i0 >> 16) | (i1 & 0xffff0000u);  // {Pjf'[2mi], Pjf'[2mi+1]}
      bf16x8 Bf_ = mkbf8(w01[ni], w23[ni], bIf, 0u);
      bf16x8 Bm_ = mkbf8(w01[ni], w23[ni], bIm, 0u);
      SF[ni] = __builtin_amdgcn_mfma_f32_16x16x32_bf16(af, Bf_, acc[mi][ni], 0, 0, 0);
      SM[ni] = __builtin_amdgcn_mfma_f32_16x16x32_bf16(am, Bm_, acc[mi][ni], 0, 0, 0);
    }

#pragma unroll
    for (int r = 0; r < 4; ++r) {
      int p = mi * 16 + quad * 4 + r;  // C/D: pair row = quad*4 + r
      float vf = 0.f, vm = 0.f;
#pragma unroll
      for (int ni = 0; ni < 2; ++ni) {
        float piJ = ulo(uJ[r][ni]), pjJ = uhi(uJ[r][ni]);
        float pf = SF[ni][r] + pjJ;
        float pm = SM[ni][r] + piJ;
        vf = fmaf(fmaxf(pf, 0.f), cW2[ni], vf);
        vm = fmaf(fmaxf(pm, 0.f), cW2[ni], vm);
      }
      vf += __shfl_xor(vf, 1);
      vf += __shfl_xor(vf, 2);
      vm += __shfl_xor(vm, 1);
      vm += __shfl_xor(vm, 2);
      if ((col & 3) == 0) {
        int part = wn2 * 4 + (col >> 2);
        sP[p * 40 + part] = vf;
        sP[p * 40 + 20 + part] = vm;
      }
    }
  }
  __syncthreads();

  // ---- final: sum 16 fwd + 16 mirror partials, symmetric store ----
  if (tid < 64) {
    int p = tid;
    const float4* pf4 = reinterpret_cast<const float4*>(sP + p * 40);
    const float4* pm4 = reinterpret_cast<const float4*>(sP + p * 40 + 20);
    float4 fa = pf4[0], fb = pf4[1], fc = pf4[2], fd = pf4[3];
    float4 ma = pm4[0], mb = pm4[1], mc = pm4[2], md = pm4[3];
    float sumF = (fa.x + fa.y + fa.z + fa.w) + (fb.x + fb.y + fb.z + fb.w) +
                 (fc.x + fc.y + fc.z + fc.w) + (fd.x + fd.y + fd.z + fd.w);
    float sumM = (ma.x + ma.y + ma.z + ma.w) + (mb.x + mb.y + mb.z + mb.w) +
                 (mc.x + mc.y + mc.z + mc.w) + (md.x + md.y + md.z + md.w);
    float val = 0.5f * (sumF + sumM) + b2v;
    int iN = I0 + (p >> 3), jN = J0 + (p & 7);
    if (iN == jN) val = -1e9f;
    out[(size_t)(rowB + iN) * 256 + jN] = val;
    out[(size_t)(rowB + jN) * 256 + iN] = val;
  }
}

extern "C" void kernel_launch(void* const* d_in, const int* in_sizes, int n_in,
                              void* d_out, int out_size, void* d_ws, size_t ws_size,
                              hipStream_t stream) {
  const float* node = (const float*)d_in[0];   // [4,256,128]
  const float* baseL = (const float*)d_in[1];  // [4,256,256]
  const float* compL = (const float*)d_in[2];  // [4,256,256]
  const float* W1 = (const float*)d_in[3];     // [516,128]
  const float* b1 = (const float*)d_in[4];     // [128]
  const float* W2 = (const float*)d_in[5];     // [128,1]
  const float* b2 = (const float*)d_in[6];     // [1]
  float* out = (float*)d_out;                  // [4,256,256] fp32

  char* ws = (char*)d_ws;
  uint32_t* Ppk = (uint32_t*)ws;                   // 512 KB packed {PiB'|Pjf'}
  uint32_t* W1f8 = (uint32_t*)(ws + (512 << 10));  // 32 KB

  pre_k<<<96, 256, 0, stream>>>(node, W1, b1, Ppk, W1f8);
  main_k<<<2112, 256, 0, stream>>>(node, baseL, compL, W1, W2, b2, W1f8, Ppk, out);
}